// Round 2
// baseline (141.126 us; speedup 1.0000x reference)
//
#include <hip/hip_runtime.h>
#include <stdint.h>

#define TSEQ 4096
#define DMODEL 1024
#define N3 3072
#define NHEADS 16
#define HDIM 64
#define WINDOW 256

typedef __attribute__((ext_vector_type(8))) short short8;
typedef __attribute__((ext_vector_type(4))) float f32x4;

__device__ __forceinline__ unsigned short f2bf(float f) {
  unsigned u = __builtin_bit_cast(unsigned, f);
  return (unsigned short)((u + 0x7fffu + ((u >> 16) & 1u)) >> 16);
}

__device__ __forceinline__ unsigned cvtpk(float lo, float hi) {
  unsigned r;
  asm("v_cvt_pk_bf16_f32 %0, %1, %2" : "=v"(r) : "v"(lo), "v"(hi));
  return r;
}

__device__ __forceinline__ f32x4 mfma16(short8 a, short8 b, f32x4 c) {
  return __builtin_amdgcn_mfma_f32_16x16x32_bf16(a, b, c, 0, 0, 0);
}

// async global->LDS, 16B per lane; lds dest must be wave-uniform base (HW adds lane*16)
__device__ __forceinline__ void g2lds16(const void* g, void* l) {
  __builtin_amdgcn_global_load_lds(
      (const __attribute__((address_space(1))) void*)(uintptr_t)g,
      (__attribute__((address_space(3))) void*)(uintptr_t)l,
      16, 0, 0);
}

// ---------------- convert / transpose ----------------

__global__ __launch_bounds__(256) void cvt_f32_bf16_v4(const float* __restrict__ in,
                                                       unsigned short* __restrict__ out) {
  int i = (blockIdx.x * 256 + threadIdx.x) * 4;
  float4 v = *(const float4*)(in + i);
  unsigned lo = cvtpk(v.x, v.y), hi = cvtpk(v.z, v.w);
  unsigned long long packed = (unsigned long long)lo | ((unsigned long long)hi << 32);
  *(unsigned long long*)(out + i) = packed;
}

// in [R][C] f32 -> out [C][R] bf16
__global__ __launch_bounds__(256) void transpose_cvt(const float* __restrict__ in,
                                                     unsigned short* __restrict__ out,
                                                     int R, int C) {
  __shared__ float tile[32][33];
  int c0 = blockIdx.x * 32;
  int r0 = blockIdx.y * 32;
  int tx = threadIdx.x, ty = threadIdx.y;
#pragma unroll
  for (int i = 0; i < 32; i += 8)
    tile[ty + i][tx] = in[(size_t)(r0 + ty + i) * C + c0 + tx];
  __syncthreads();
#pragma unroll
  for (int i = 0; i < 32; i += 8)
    out[(size_t)(c0 + ty + i) * R + r0 + tx] = f2bf(tile[tx][ty + i]);
}

// ---------------- GEMM: C[M][N] = A[M][K=1024] * BT[N][K]^T + bias ----------------
// EPI=0: scatter to Q[h][t][d] (pre-scaled by 1/8), K[h][t][d], VT[h][d][t] (bf16)
// EPI=1: f32 out [M][1024]

template <int EPI>
__global__ __launch_bounds__(256)
void gemm_bf16_128(const unsigned short* __restrict__ A,
                   const unsigned short* __restrict__ BT,
                   const float* __restrict__ bias,
                   unsigned short* __restrict__ oQ,
                   unsigned short* __restrict__ oK,
                   unsigned short* __restrict__ oVT,
                   float* __restrict__ oF) {
  __shared__ unsigned short Asm[128 * 32];
  __shared__ unsigned short Bsm[128 * 32];
  const int K = 1024;
  // XCD-aware swizzle: each XCD gets a contiguous chunk of tile space
  int nwg = gridDim.x * gridDim.y;            // 768 or 256, both % 8 == 0
  int flat = blockIdx.y * gridDim.x + blockIdx.x;
  int swz = (flat & 7) * (nwg >> 3) + (flat >> 3);
  int bx = swz % gridDim.x, by = swz / gridDim.x;
  int m0 = bx * 128;
  int n0 = by * 128;
  int tid = threadIdx.x;
  int w = tid >> 6, lane = tid & 63;
  int l15 = lane & 15, l4 = lane >> 4;
  int wm = (w >> 1) * 64, wn = (w & 1) * 64;

  f32x4 acc[4][4];
#pragma unroll
  for (int i = 0; i < 4; i++)
#pragma unroll
    for (int j = 0; j < 4; j++) acc[i][j] = (f32x4){0.f, 0.f, 0.f, 0.f};

  const unsigned short* aSrc = A + (size_t)(m0 + w * 32 + (lane >> 2)) * K + (lane & 3) * 8;
  const unsigned short* bSrc = BT + (size_t)(n0 + w * 32 + (lane >> 2)) * K + (lane & 3) * 8;
  unsigned short* aDst0 = &Asm[(w * 2 + 0) * 512];
  unsigned short* aDst1 = &Asm[(w * 2 + 1) * 512];
  unsigned short* bDst0 = &Bsm[(w * 2 + 0) * 512];
  unsigned short* bDst1 = &Bsm[(w * 2 + 1) * 512];

  for (int k0 = 0; k0 < K; k0 += 32) {
    g2lds16(aSrc + k0, aDst0);
    g2lds16(aSrc + 16 * K + k0, aDst1);
    g2lds16(bSrc + k0, bDst0);
    g2lds16(bSrc + 16 * K + k0, bDst1);
    __syncthreads();
    short8 af[4], bfr[4];
#pragma unroll
    for (int mi = 0; mi < 4; mi++)
      af[mi] = *(const short8*)&Asm[(wm + mi * 16 + l15) * 32 + l4 * 8];
#pragma unroll
    for (int ni = 0; ni < 4; ni++)
      bfr[ni] = *(const short8*)&Bsm[(wn + ni * 16 + l15) * 32 + l4 * 8];
#pragma unroll
    for (int mi = 0; mi < 4; mi++)
#pragma unroll
      for (int ni = 0; ni < 4; ni++)
        acc[mi][ni] = mfma16(af[mi], bfr[ni], acc[mi][ni]);
    __syncthreads();
  }

#pragma unroll
  for (int ni = 0; ni < 4; ni++) {
    int nn = n0 + wn + ni * 16 + l15;
    float bv = bias[nn];
#pragma unroll
    for (int mi = 0; mi < 4; mi++) {
#pragma unroll
      for (int r = 0; r < 4; r++) {
        int mm = m0 + wm + mi * 16 + l4 * 4 + r;
        float v = acc[mi][ni][r] + bv;
        if (EPI == 0) {
          int c = nn & 1023;
          int hh = c >> 6, dd = c & 63;
          if (nn < 1024) {
            // fold 1/sqrt(HDIM)=0.125 into Q (power of two: exact in bf16)
            oQ[((size_t)hh * TSEQ + mm) * 64 + dd] = f2bf(v * 0.125f);
          } else if (nn < 2048) {
            oK[((size_t)hh * TSEQ + mm) * 64 + dd] = f2bf(v);
          } else {
            oVT[((size_t)hh * 64 + dd) * TSEQ + mm] = f2bf(v);
          }
        } else {
          oF[(size_t)mm * 1024 + nn] = v;
        }
      }
    }
  }
}

// ---------------- sliding-window attention (swapped-operand flash) ----------------
// grid 1024 blocks (XCD-swizzled -> (h, qb)), 4 waves; wave w owns q rows qb*64+w*16..+15
// S^T = mfma(A=K, B=Q): lane holds S[q = qrow0+(lane&15)][key = kbase+ni*16+(lane>>4)*4+r]
//   -> row softmax = in-register reduce over 16 + shfl_xor(16) + shfl_xor(32)
// PV swapped too: o^T = mfma(A=Vt, B=P^T): alpha rescale + 1/l stay lane-local (q=lane&15)

__global__ __launch_bounds__(256)
void attn_swa(const unsigned short* __restrict__ Qa,
              const unsigned short* __restrict__ Ka,
              const unsigned short* __restrict__ Vt,
              unsigned short* __restrict__ Y) {
  __shared__ unsigned char Pl[4][2048];
  int flat = blockIdx.x;
  int swz = (flat & 7) * 128 + (flat >> 3);   // 1024 blocks, bijective
  int h = swz >> 6, qb = swz & 63;
  int w = threadIdx.x >> 6, lane = threadIdx.x & 63;
  int l15 = lane & 15, l4 = lane >> 4;
  int qrow0 = qb * 64 + w * 16;
  int q = qrow0 + l15;

  const unsigned short* qp = Qa + ((size_t)h * TSEQ + q) * 64 + l4 * 8;
  short8 qf0 = *(const short8*)qp;
  short8 qf1 = *(const short8*)(qp + 32);

  float m = -1e30f, lsum = 0.f;
  f32x4 o[4];
#pragma unroll
  for (int ni = 0; ni < 4; ni++) o[ni] = (f32x4){0.f, 0.f, 0.f, 0.f};

  unsigned char* pw = Pl[w];
  int xw = (l15 & 7) << 4;  // row-XOR swizzle (row = l15 on BOTH write and read)

  // MODE: 0 = interior (no mask), 1 = window edge (q-key<256), 2 = causal diag (key<=q)
  auto tile = [&](int kt, int MODE) {
    int kbase = kt * 64;
    const unsigned short* kp = Ka + ((size_t)h * TSEQ + kbase) * 64;
    short8 kf0[4], kf1[4];
#pragma unroll
    for (int ni = 0; ni < 4; ni++) {
      const unsigned short* kr = kp + (ni * 16 + l15) * 64 + l4 * 8;
      kf0[ni] = *(const short8*)kr;
      kf1[ni] = *(const short8*)(kr + 32);
    }
    // V loads issued before QK so their latency hides under softmax
    const unsigned short* vp = Vt + (size_t)h * 64 * TSEQ + kbase;
    short8 vf0[4], vf1[4];
#pragma unroll
    for (int ni = 0; ni < 4; ni++) {
      const unsigned short* vr = vp + (size_t)(ni * 16 + l15) * TSEQ + l4 * 8;
      vf0[ni] = *(const short8*)vr;
      vf1[ni] = *(const short8*)(vr + 32);
    }
    f32x4 s[4];
#pragma unroll
    for (int ni = 0; ni < 4; ni++) {
      f32x4 z = (f32x4){0.f, 0.f, 0.f, 0.f};
      z = mfma16(kf0[ni], qf0, z);
      s[ni] = mfma16(kf1[ni], qf1, z);
    }
    if (MODE != 0) {
#pragma unroll
      for (int ni = 0; ni < 4; ni++)
#pragma unroll
        for (int r = 0; r < 4; r++) {
          int key = kbase + ni * 16 + l4 * 4 + r;
          bool ok = (MODE == 2) ? (key <= q) : (q - key < WINDOW);
          s[ni][r] = ok ? s[ni][r] : -1e30f;
        }
    }
    // row max: in-register tree + 2 shfl
    float pm0 = fmaxf(fmaxf(s[0][0], s[0][1]), fmaxf(s[0][2], s[0][3]));
    float pm1 = fmaxf(fmaxf(s[1][0], s[1][1]), fmaxf(s[1][2], s[1][3]));
    float pm2 = fmaxf(fmaxf(s[2][0], s[2][1]), fmaxf(s[2][2], s[2][3]));
    float pm3 = fmaxf(fmaxf(s[3][0], s[3][1]), fmaxf(s[3][2], s[3][3]));
    float pm = fmaxf(fmaxf(pm0, pm1), fmaxf(pm2, pm3));
    pm = fmaxf(pm, __shfl_xor(pm, 16, 64));
    pm = fmaxf(pm, __shfl_xor(pm, 32, 64));
    float mn = fmaxf(m, pm);
    float alpha = __expf(m - mn);
    m = mn;
    float rs = 0.f;
#pragma unroll
    for (int ni = 0; ni < 4; ni++)
#pragma unroll
      for (int r = 0; r < 4; r++) {
        float p = __expf(s[ni][r] - mn);
        s[ni][r] = p;
        rs += p;
      }
    rs += __shfl_xor(rs, 16, 64);
    rs += __shfl_xor(rs, 32, 64);
    lsum = lsum * alpha + rs;
    // P -> LDS: 4x ds_write_b64 (cvt_pk packed), row-XOR swizzled
#pragma unroll
    for (int ni = 0; ni < 4; ni++) {
      unsigned lo = cvtpk(s[ni][0], s[ni][1]);
      unsigned hi = cvtpk(s[ni][2], s[ni][3]);
      unsigned long long pv = (unsigned long long)lo | ((unsigned long long)hi << 32);
      *(unsigned long long*)(pw + l15 * 128 + ((ni * 32 + l4 * 8) ^ xw)) = pv;
    }
    short8 pa0 = *(const short8*)(pw + l15 * 128 + ((l4 * 16) ^ xw));
    short8 pa1 = *(const short8*)(pw + l15 * 128 + ((64 + l4 * 16) ^ xw));
#pragma unroll
    for (int ni = 0; ni < 4; ni++)
#pragma unroll
      for (int r = 0; r < 4; r++) o[ni][r] *= alpha;
#pragma unroll
    for (int ni = 0; ni < 4; ni++) {
      o[ni] = mfma16(vf0[ni], pa0, o[ni]);
      o[ni] = mfma16(vf1[ni], pa1, o[ni]);
    }
  };

  if (qb >= 4) tile(qb - 4, 1);             // window edge tile
  int ktA = qb >= 4 ? qb - 3 : 0;
  for (int kt = ktA; kt < qb; ++kt) tile(kt, 0);  // interior: provably unmasked
  tile(qb, 2);                               // causal diagonal tile

  // epilogue: o[ni][r] = O[q][d = ni*16 + l4*4 + r], q = qrow0 + l15 (lane-local l)
  float inv = 1.f / lsum;
#pragma unroll
  for (int ni = 0; ni < 4; ni++) {
    unsigned lo = cvtpk(o[ni][0] * inv, o[ni][1] * inv);
    unsigned hi = cvtpk(o[ni][2] * inv, o[ni][3] * inv);
    unsigned long long yv = (unsigned long long)lo | ((unsigned long long)hi << 32);
    *(unsigned long long*)(Y + (size_t)q * DMODEL + h * 64 + ni * 16 + l4 * 4) = yv;
  }
}

// ---------------- launch ----------------

extern "C" void kernel_launch(void* const* d_in, const int* in_sizes, int n_in,
                              void* d_out, int out_size, void* d_ws, size_t ws_size,
                              hipStream_t stream) {
  const float* x = (const float*)d_in[0];
  const float* Wqkv = (const float*)d_in[1];
  const float* bqkv = (const float*)d_in[2];
  const float* Wproj = (const float*)d_in[3];
  const float* bproj = (const float*)d_in[4];
  float* out = (float*)d_out;

  unsigned short* ws = (unsigned short*)d_ws;
  unsigned short* xb = ws;                                        // [4096][1024]
  unsigned short* wqkvT = xb + (size_t)TSEQ * DMODEL;             // [3072][1024]
  unsigned short* wprojT = wqkvT + (size_t)N3 * DMODEL;           // [1024][1024]
  unsigned short* qarr = wprojT + (size_t)DMODEL * DMODEL;        // [16][4096][64] (pre-scaled 1/8)
  unsigned short* karr = qarr + (size_t)NHEADS * TSEQ * HDIM;     // [16][4096][64]
  unsigned short* vtarr = karr + (size_t)NHEADS * TSEQ * HDIM;    // [16][64][4096]
  unsigned short* yarr = vtarr + (size_t)NHEADS * TSEQ * HDIM;    // [4096][1024]

  cvt_f32_bf16_v4<<<(TSEQ * DMODEL) / 1024, 256, 0, stream>>>(x, xb);
  transpose_cvt<<<dim3(N3 / 32, DMODEL / 32), dim3(32, 8), 0, stream>>>(Wqkv, wqkvT, DMODEL, N3);
  transpose_cvt<<<dim3(DMODEL / 32, DMODEL / 32), dim3(32, 8), 0, stream>>>(Wproj, wprojT, DMODEL, DMODEL);
  gemm_bf16_128<0><<<dim3(TSEQ / 128, N3 / 128), 256, 0, stream>>>(xb, wqkvT, bqkv, qarr, karr, vtarr, nullptr);
  attn_swa<<<1024, 256, 0, stream>>>(qarr, karr, vtarr, yarr);
  gemm_bf16_128<1><<<dim3(TSEQ / 128, DMODEL / 128), 256, 0, stream>>>(yarr, wprojT, bproj, nullptr, nullptr, nullptr, out);
}

// Round 3
// 128.283 us; speedup vs baseline: 1.1001x; 1.1001x over previous
//
#include <hip/hip_runtime.h>
#include <stdint.h>

#define TSEQ 4096
#define DMODEL 1024
#define N3 3072
#define NHEADS 16
#define HDIM 64
#define WINDOW 256

typedef __attribute__((ext_vector_type(8))) short short8;
typedef __attribute__((ext_vector_type(4))) float f32x4;

__device__ __forceinline__ unsigned short f2bf(float f) {
  unsigned u = __builtin_bit_cast(unsigned, f);
  return (unsigned short)((u + 0x7fffu + ((u >> 16) & 1u)) >> 16);
}

__device__ __forceinline__ unsigned cvtpk(float lo, float hi) {
  unsigned r;
  asm("v_cvt_pk_bf16_f32 %0, %1, %2" : "=v"(r) : "v"(lo), "v"(hi));
  return r;
}

__device__ __forceinline__ f32x4 mfma16(short8 a, short8 b, f32x4 c) {
  return __builtin_amdgcn_mfma_f32_16x16x32_bf16(a, b, c, 0, 0, 0);
}

// async global->LDS, 16B per lane; lds dest must be wave-uniform base (HW adds lane*16)
__device__ __forceinline__ void g2lds16(const void* g, void* l) {
  __builtin_amdgcn_global_load_lds(
      (const __attribute__((address_space(1))) void*)(uintptr_t)g,
      (__attribute__((address_space(3))) void*)(uintptr_t)l,
      16, 0, 0);
}

// ---------------- convert / transpose ----------------

__global__ __launch_bounds__(256) void cvt_f32_bf16_v4(const float* __restrict__ in,
                                                       unsigned short* __restrict__ out) {
  int i = (blockIdx.x * 256 + threadIdx.x) * 4;
  float4 v = *(const float4*)(in + i);
  unsigned lo = cvtpk(v.x, v.y), hi = cvtpk(v.z, v.w);
  unsigned long long packed = (unsigned long long)lo | ((unsigned long long)hi << 32);
  *(unsigned long long*)(out + i) = packed;
}

// fused: Wqkv [1024][3072] -> [3072][1024] bf16, Wproj [1024][1024] -> [1024][1024] bf16
__global__ __launch_bounds__(256) void transpose_cvt2(const float* __restrict__ Wqkv,
                                                      const float* __restrict__ Wproj,
                                                      unsigned short* __restrict__ oQkvT,
                                                      unsigned short* __restrict__ oProjT) {
  __shared__ float tile[32][33];
  int bx = blockIdx.x;
  const float* in;
  unsigned short* out;
  int C;
  if (bx < 96) {
    in = Wqkv; out = oQkvT; C = N3;
  } else {
    bx -= 96; in = Wproj; out = oProjT; C = DMODEL;
  }
  const int R = DMODEL;
  int c0 = bx * 32;
  int r0 = blockIdx.y * 32;
  int tx = threadIdx.x, ty = threadIdx.y;
#pragma unroll
  for (int i = 0; i < 32; i += 8)
    tile[ty + i][tx] = in[(size_t)(r0 + ty + i) * C + c0 + tx];
  __syncthreads();
#pragma unroll
  for (int i = 0; i < 32; i += 8)
    out[(size_t)(c0 + ty + i) * R + r0 + tx] = f2bf(tile[tx][ty + i]);
}

// ---------------- GEMM: C[M][N] = A[M][K=1024] * BT[N][K]^T + bias ----------------
// EPI=0: scatter to Q[h][t][d] (pre-scaled by 1/8), K[h][t][d], VT[h][d][t] (bf16)
// EPI=1: f32 out [M][1024]
// BK=64 as two independent BK=32 buffer pairs (64B row stride -> only 2-way LDS
// aliasing, free per m136); halves barrier count vs BK=32.

template <int EPI>
__global__ __launch_bounds__(256)
void gemm_bf16_128(const unsigned short* __restrict__ A,
                   const unsigned short* __restrict__ BT,
                   const float* __restrict__ bias,
                   unsigned short* __restrict__ oQ,
                   unsigned short* __restrict__ oK,
                   unsigned short* __restrict__ oVT,
                   float* __restrict__ oF) {
  __shared__ unsigned short Asm[2][128 * 32];
  __shared__ unsigned short Bsm[2][128 * 32];
  const int K = 1024;
  int m0 = blockIdx.x * 128;   // no XCD swizzle: default bx%8 partitioning already
  int n0 = blockIdx.y * 128;   // splits A-panels across XCDs (round-2 post-mortem)
  int tid = threadIdx.x;
  int w = tid >> 6, lane = tid & 63;
  int l15 = lane & 15, l4 = lane >> 4;
  int wm = (w >> 1) * 64, wn = (w & 1) * 64;

  f32x4 acc[4][4];
#pragma unroll
  for (int i = 0; i < 4; i++)
#pragma unroll
    for (int j = 0; j < 4; j++) acc[i][j] = (f32x4){0.f, 0.f, 0.f, 0.f};

  const unsigned short* aSrc = A + (size_t)(m0 + w * 32 + (lane >> 2)) * K + (lane & 3) * 8;
  const unsigned short* bSrc = BT + (size_t)(n0 + w * 32 + (lane >> 2)) * K + (lane & 3) * 8;

  for (int k0 = 0; k0 < K; k0 += 64) {
    // stage both 32-wide halves (8x 1KB wave-chunks)
#pragma unroll
    for (int hf = 0; hf < 2; hf++) {
      g2lds16(aSrc + k0 + hf * 32, &Asm[hf][(w * 2 + 0) * 512]);
      g2lds16(aSrc + 16 * K + k0 + hf * 32, &Asm[hf][(w * 2 + 1) * 512]);
      g2lds16(bSrc + k0 + hf * 32, &Bsm[hf][(w * 2 + 0) * 512]);
      g2lds16(bSrc + 16 * K + k0 + hf * 32, &Bsm[hf][(w * 2 + 1) * 512]);
    }
    __syncthreads();
#pragma unroll
    for (int hf = 0; hf < 2; hf++) {
      short8 af[4], bfr[4];
#pragma unroll
      for (int mi = 0; mi < 4; mi++)
        af[mi] = *(const short8*)&Asm[hf][(wm + mi * 16 + l15) * 32 + l4 * 8];
#pragma unroll
      for (int ni = 0; ni < 4; ni++)
        bfr[ni] = *(const short8*)&Bsm[hf][(wn + ni * 16 + l15) * 32 + l4 * 8];
#pragma unroll
      for (int mi = 0; mi < 4; mi++)
#pragma unroll
        for (int ni = 0; ni < 4; ni++)
          acc[mi][ni] = mfma16(af[mi], bfr[ni], acc[mi][ni]);
    }
    __syncthreads();
  }

#pragma unroll
  for (int ni = 0; ni < 4; ni++) {
    int nn = n0 + wn + ni * 16 + l15;
    float bv = bias[nn];
    int c = nn & 1023;
    int hh = c >> 6, dd = c & 63;
#pragma unroll
    for (int mi = 0; mi < 4; mi++) {
      int mm = m0 + wm + mi * 16 + l4 * 4;
      float v0 = acc[mi][ni][0] + bv;
      float v1 = acc[mi][ni][1] + bv;
      float v2 = acc[mi][ni][2] + bv;
      float v3 = acc[mi][ni][3] + bv;
      if (EPI == 1) {
        oF[(size_t)(mm + 0) * 1024 + nn] = v0;
        oF[(size_t)(mm + 1) * 1024 + nn] = v1;
        oF[(size_t)(mm + 2) * 1024 + nn] = v2;
        oF[(size_t)(mm + 3) * 1024 + nn] = v3;
      } else if (nn < 1024) {
        // fold 1/sqrt(HDIM)=0.125 into Q (power of two: exact in bf16)
        oQ[((size_t)hh * TSEQ + mm + 0) * 64 + dd] = f2bf(v0 * 0.125f);
        oQ[((size_t)hh * TSEQ + mm + 1) * 64 + dd] = f2bf(v1 * 0.125f);
        oQ[((size_t)hh * TSEQ + mm + 2) * 64 + dd] = f2bf(v2 * 0.125f);
        oQ[((size_t)hh * TSEQ + mm + 3) * 64 + dd] = f2bf(v3 * 0.125f);
      } else if (nn < 2048) {
        oK[((size_t)hh * TSEQ + mm + 0) * 64 + dd] = f2bf(v0);
        oK[((size_t)hh * TSEQ + mm + 1) * 64 + dd] = f2bf(v1);
        oK[((size_t)hh * TSEQ + mm + 2) * 64 + dd] = f2bf(v2);
        oK[((size_t)hh * TSEQ + mm + 3) * 64 + dd] = f2bf(v3);
      } else {
        // VT row dd, cols mm..mm+3 contiguous -> one packed 8B store
        unsigned lo = cvtpk(v0, v1), hi = cvtpk(v2, v3);
        unsigned long long pv = (unsigned long long)lo | ((unsigned long long)hi << 32);
        *(unsigned long long*)(oVT + ((size_t)hh * 64 + dd) * TSEQ + mm) = pv;
      }
    }
  }
}

// ---------------- sliding-window attention (swapped-operand flash) ----------------
// grid 1024 blocks (XCD-swizzled -> (h, qb)), 4 waves; wave w owns q rows qb*64+w*16..+15
// S^T = mfma(A=K, B=Q): lane holds S[q = qrow0+(lane&15)][key = kbase+ni*16+(lane>>4)*4+r]
// PV swapped too: o^T = mfma(A=Vt, B=P^T): alpha rescale + 1/l stay lane-local (q=lane&15)

__global__ __launch_bounds__(256)
void attn_swa(const unsigned short* __restrict__ Qa,
              const unsigned short* __restrict__ Ka,
              const unsigned short* __restrict__ Vt,
              unsigned short* __restrict__ Y) {
  __shared__ unsigned char Pl[4][2048];
  int flat = blockIdx.x;
  int swz = (flat & 7) * 128 + (flat >> 3);   // 1024 blocks, bijective; 2 heads/XCD
  int h = swz >> 6, qb = swz & 63;
  int w = threadIdx.x >> 6, lane = threadIdx.x & 63;
  int l15 = lane & 15, l4 = lane >> 4;
  int qrow0 = qb * 64 + w * 16;
  int q = qrow0 + l15;

  const unsigned short* qp = Qa + ((size_t)h * TSEQ + q) * 64 + l4 * 8;
  short8 qf0 = *(const short8*)qp;
  short8 qf1 = *(const short8*)(qp + 32);

  float m = -1e30f, lsum = 0.f;
  f32x4 o[4];
#pragma unroll
  for (int ni = 0; ni < 4; ni++) o[ni] = (f32x4){0.f, 0.f, 0.f, 0.f};

  unsigned char* pw = Pl[w];
  int xw = (l15 & 7) << 4;  // row-XOR swizzle (row = l15 on BOTH write and read)

  // MODE: 0 = interior (no mask), 1 = window edge (q-key<256), 2 = causal diag (key<=q)
  auto tile = [&](int kt, int MODE) {
    int kbase = kt * 64;
    const unsigned short* kp = Ka + ((size_t)h * TSEQ + kbase) * 64;
    short8 kf0[4], kf1[4];
#pragma unroll
    for (int ni = 0; ni < 4; ni++) {
      const unsigned short* kr = kp + (ni * 16 + l15) * 64 + l4 * 8;
      kf0[ni] = *(const short8*)kr;
      kf1[ni] = *(const short8*)(kr + 32);
    }
    // V loads issued before QK so their latency hides under softmax
    const unsigned short* vp = Vt + (size_t)h * 64 * TSEQ + kbase;
    short8 vf0[4], vf1[4];
#pragma unroll
    for (int ni = 0; ni < 4; ni++) {
      const unsigned short* vr = vp + (size_t)(ni * 16 + l15) * TSEQ + l4 * 8;
      vf0[ni] = *(const short8*)vr;
      vf1[ni] = *(const short8*)(vr + 32);
    }
    f32x4 s[4];
#pragma unroll
    for (int ni = 0; ni < 4; ni++) {
      f32x4 z = (f32x4){0.f, 0.f, 0.f, 0.f};
      z = mfma16(kf0[ni], qf0, z);
      s[ni] = mfma16(kf1[ni], qf1, z);
    }
    if (MODE != 0) {
#pragma unroll
      for (int ni = 0; ni < 4; ni++)
#pragma unroll
        for (int r = 0; r < 4; r++) {
          int key = kbase + ni * 16 + l4 * 4 + r;
          bool ok = (MODE == 2) ? (key <= q) : (q - key < WINDOW);
          s[ni][r] = ok ? s[ni][r] : -1e30f;
        }
    }
    // row max: in-register tree + 2 shfl
    float pm0 = fmaxf(fmaxf(s[0][0], s[0][1]), fmaxf(s[0][2], s[0][3]));
    float pm1 = fmaxf(fmaxf(s[1][0], s[1][1]), fmaxf(s[1][2], s[1][3]));
    float pm2 = fmaxf(fmaxf(s[2][0], s[2][1]), fmaxf(s[2][2], s[2][3]));
    float pm3 = fmaxf(fmaxf(s[3][0], s[3][1]), fmaxf(s[3][2], s[3][3]));
    float pm = fmaxf(fmaxf(pm0, pm1), fmaxf(pm2, pm3));
    pm = fmaxf(pm, __shfl_xor(pm, 16, 64));
    pm = fmaxf(pm, __shfl_xor(pm, 32, 64));
    float mn = fmaxf(m, pm);
    float alpha = __expf(m - mn);
    m = mn;
    float rs = 0.f;
#pragma unroll
    for (int ni = 0; ni < 4; ni++)
#pragma unroll
      for (int r = 0; r < 4; r++) {
        float p = __expf(s[ni][r] - mn);
        s[ni][r] = p;
        rs += p;
      }
    rs += __shfl_xor(rs, 16, 64);
    rs += __shfl_xor(rs, 32, 64);
    lsum = lsum * alpha + rs;
    // P -> LDS: 4x ds_write_b64 (cvt_pk packed), row-XOR swizzled
#pragma unroll
    for (int ni = 0; ni < 4; ni++) {
      unsigned lo = cvtpk(s[ni][0], s[ni][1]);
      unsigned hi = cvtpk(s[ni][2], s[ni][3]);
      unsigned long long pv = (unsigned long long)lo | ((unsigned long long)hi << 32);
      *(unsigned long long*)(pw + l15 * 128 + ((ni * 32 + l4 * 8) ^ xw)) = pv;
    }
    short8 pa0 = *(const short8*)(pw + l15 * 128 + ((l4 * 16) ^ xw));
    short8 pa1 = *(const short8*)(pw + l15 * 128 + ((64 + l4 * 16) ^ xw));
#pragma unroll
    for (int ni = 0; ni < 4; ni++)
#pragma unroll
      for (int r = 0; r < 4; r++) o[ni][r] *= alpha;
#pragma unroll
    for (int ni = 0; ni < 4; ni++) {
      o[ni] = mfma16(vf0[ni], pa0, o[ni]);
      o[ni] = mfma16(vf1[ni], pa1, o[ni]);
    }
  };

  if (qb >= 4) tile(qb - 4, 1);             // window edge tile
  int ktA = qb >= 4 ? qb - 3 : 0;
  for (int kt = ktA; kt < qb; ++kt) tile(kt, 0);  // interior: provably unmasked
  tile(qb, 2);                               // causal diagonal tile

  // epilogue: o[ni][r] = O[q][d = ni*16 + l4*4 + r], q = qrow0 + l15 (lane-local l)
  float inv = 1.f / lsum;
#pragma unroll
  for (int ni = 0; ni < 4; ni++) {
    unsigned lo = cvtpk(o[ni][0] * inv, o[ni][1] * inv);
    unsigned hi = cvtpk(o[ni][2] * inv, o[ni][3] * inv);
    unsigned long long yv = (unsigned long long)lo | ((unsigned long long)hi << 32);
    *(unsigned long long*)(Y + (size_t)q * DMODEL + h * 64 + ni * 16 + l4 * 4) = yv;
  }
}

// ---------------- launch ----------------

extern "C" void kernel_launch(void* const* d_in, const int* in_sizes, int n_in,
                              void* d_out, int out_size, void* d_ws, size_t ws_size,
                              hipStream_t stream) {
  const float* x = (const float*)d_in[0];
  const float* Wqkv = (const float*)d_in[1];
  const float* bqkv = (const float*)d_in[2];
  const float* Wproj = (const float*)d_in[3];
  const float* bproj = (const float*)d_in[4];
  float* out = (float*)d_out;

  unsigned short* ws = (unsigned short*)d_ws;
  unsigned short* xb = ws;                                        // [4096][1024]
  unsigned short* wqkvT = xb + (size_t)TSEQ * DMODEL;             // [3072][1024]
  unsigned short* wprojT = wqkvT + (size_t)N3 * DMODEL;           // [1024][1024]
  unsigned short* qarr = wprojT + (size_t)DMODEL * DMODEL;        // [16][4096][64] (pre-scaled 1/8)
  unsigned short* karr = qarr + (size_t)NHEADS * TSEQ * HDIM;     // [16][4096][64]
  unsigned short* vtarr = karr + (size_t)NHEADS * TSEQ * HDIM;    // [16][64][4096]
  unsigned short* yarr = vtarr + (size_t)NHEADS * TSEQ * HDIM;    // [4096][1024]

  cvt_f32_bf16_v4<<<(TSEQ * DMODEL) / 1024, 256, 0, stream>>>(x, xb);
  transpose_cvt2<<<dim3(128, 32), dim3(32, 8), 0, stream>>>(Wqkv, Wproj, wqkvT, wprojT);
  gemm_bf16_128<0><<<dim3(TSEQ / 128, N3 / 128), 256, 0, stream>>>(xb, wqkvT, bqkv, qarr, karr, vtarr, nullptr);
  attn_swa<<<1024, 256, 0, stream>>>(qarr, karr, vtarr, yarr);
  gemm_bf16_128<1><<<dim3(TSEQ / 128, DMODEL / 128), 256, 0, stream>>>(yarr, wprojT, bproj, nullptr, nullptr, nullptr, out);
}

// Round 4
// 96.560 us; speedup vs baseline: 1.4615x; 1.3285x over previous
//
#include <hip/hip_runtime.h>
#include <stdint.h>

#define TSEQ 4096
#define DMODEL 1024
#define N3 3072
#define NHEADS 16
#define HDIM 64
#define WINDOW 256

typedef __attribute__((ext_vector_type(8))) short short8;
typedef __attribute__((ext_vector_type(4))) float f32x4;

__device__ __forceinline__ unsigned short f2bf(float f) {
  unsigned u = __builtin_bit_cast(unsigned, f);
  return (unsigned short)((u + 0x7fffu + ((u >> 16) & 1u)) >> 16);
}

__device__ __forceinline__ unsigned cvtpk(float lo, float hi) {
  unsigned r;
  asm("v_cvt_pk_bf16_f32 %0, %1, %2" : "=v"(r) : "v"(lo), "v"(hi));
  return r;
}

__device__ __forceinline__ f32x4 mfma16(short8 a, short8 b, f32x4 c) {
  return __builtin_amdgcn_mfma_f32_16x16x32_bf16(a, b, c, 0, 0, 0);
}

// async global->LDS, 16B per lane; lds dest must be wave-uniform base (HW adds lane*16)
__device__ __forceinline__ void g2lds16(const void* g, void* l) {
  __builtin_amdgcn_global_load_lds(
      (const __attribute__((address_space(1))) void*)(uintptr_t)g,
      (__attribute__((address_space(3))) void*)(uintptr_t)l,
      16, 0, 0);
}

// ---------------- convert / transpose ----------------

__global__ __launch_bounds__(256) void cvt_f32_bf16_v4(const float* __restrict__ in,
                                                       unsigned short* __restrict__ out) {
  int i = (blockIdx.x * 256 + threadIdx.x) * 4;
  float4 v = *(const float4*)(in + i);
  unsigned lo = cvtpk(v.x, v.y), hi = cvtpk(v.z, v.w);
  unsigned long long packed = (unsigned long long)lo | ((unsigned long long)hi << 32);
  *(unsigned long long*)(out + i) = packed;
}

// fused: Wqkv [1024][3072] -> [3072][1024] bf16, Wproj [1024][1024] -> [1024][1024] bf16
__global__ __launch_bounds__(256) void transpose_cvt2(const float* __restrict__ Wqkv,
                                                      const float* __restrict__ Wproj,
                                                      unsigned short* __restrict__ oQkvT,
                                                      unsigned short* __restrict__ oProjT) {
  __shared__ float tile[32][33];
  int bx = blockIdx.x;
  const float* in;
  unsigned short* out;
  int C;
  if (bx < 96) {
    in = Wqkv; out = oQkvT; C = N3;
  } else {
    bx -= 96; in = Wproj; out = oProjT; C = DMODEL;
  }
  const int R = DMODEL;
  int c0 = bx * 32;
  int r0 = blockIdx.y * 32;
  int tx = threadIdx.x, ty = threadIdx.y;
#pragma unroll
  for (int i = 0; i < 32; i += 8)
    tile[ty + i][tx] = in[(size_t)(r0 + ty + i) * C + c0 + tx];
  __syncthreads();
#pragma unroll
  for (int i = 0; i < 32; i += 8)
    out[(size_t)(c0 + ty + i) * R + r0 + tx] = f2bf(tile[tx][ty + i]);
}

// ---------------- GEMM: C[M][N] = A[M][K=1024] * BT[N][K]^T + bias ----------------
// EPI=0: scatter to Q[h][t][d] (pre-scaled by 1/8), K[h][t][d], VT[h][d][t] (bf16)
// EPI=1: f32 out [M][1024]

template <int EPI>
__global__ __launch_bounds__(256)
void gemm_bf16_128(const unsigned short* __restrict__ A,
                   const unsigned short* __restrict__ BT,
                   const float* __restrict__ bias,
                   unsigned short* __restrict__ oQ,
                   unsigned short* __restrict__ oK,
                   unsigned short* __restrict__ oVT,
                   float* __restrict__ oF) {
  __shared__ unsigned short Asm[2][128 * 32];
  __shared__ unsigned short Bsm[2][128 * 32];
  const int K = 1024;
  int m0 = blockIdx.x * 128;   // no XCD swizzle: default bx%8 partitioning already
  int n0 = blockIdx.y * 128;   // splits A-panels across XCDs (round-2 post-mortem)
  int tid = threadIdx.x;
  int w = tid >> 6, lane = tid & 63;
  int l15 = lane & 15, l4 = lane >> 4;
  int wm = (w >> 1) * 64, wn = (w & 1) * 64;

  f32x4 acc[4][4];
#pragma unroll
  for (int i = 0; i < 4; i++)
#pragma unroll
    for (int j = 0; j < 4; j++) acc[i][j] = (f32x4){0.f, 0.f, 0.f, 0.f};

  const unsigned short* aSrc = A + (size_t)(m0 + w * 32 + (lane >> 2)) * K + (lane & 3) * 8;
  const unsigned short* bSrc = BT + (size_t)(n0 + w * 32 + (lane >> 2)) * K + (lane & 3) * 8;

  for (int k0 = 0; k0 < K; k0 += 64) {
#pragma unroll
    for (int hf = 0; hf < 2; hf++) {
      g2lds16(aSrc + k0 + hf * 32, &Asm[hf][(w * 2 + 0) * 512]);
      g2lds16(aSrc + 16 * K + k0 + hf * 32, &Asm[hf][(w * 2 + 1) * 512]);
      g2lds16(bSrc + k0 + hf * 32, &Bsm[hf][(w * 2 + 0) * 512]);
      g2lds16(bSrc + 16 * K + k0 + hf * 32, &Bsm[hf][(w * 2 + 1) * 512]);
    }
    __syncthreads();
#pragma unroll
    for (int hf = 0; hf < 2; hf++) {
      short8 af[4], bfr[4];
#pragma unroll
      for (int mi = 0; mi < 4; mi++)
        af[mi] = *(const short8*)&Asm[hf][(wm + mi * 16 + l15) * 32 + l4 * 8];
#pragma unroll
      for (int ni = 0; ni < 4; ni++)
        bfr[ni] = *(const short8*)&Bsm[hf][(wn + ni * 16 + l15) * 32 + l4 * 8];
#pragma unroll
      for (int mi = 0; mi < 4; mi++)
#pragma unroll
        for (int ni = 0; ni < 4; ni++)
          acc[mi][ni] = mfma16(af[mi], bfr[ni], acc[mi][ni]);
    }
    __syncthreads();
  }

#pragma unroll
  for (int ni = 0; ni < 4; ni++) {
    int nn = n0 + wn + ni * 16 + l15;
    float bv = bias[nn];
    int c = nn & 1023;
    int hh = c >> 6, dd = c & 63;
#pragma unroll
    for (int mi = 0; mi < 4; mi++) {
      int mm = m0 + wm + mi * 16 + l4 * 4;
      float v0 = acc[mi][ni][0] + bv;
      float v1 = acc[mi][ni][1] + bv;
      float v2 = acc[mi][ni][2] + bv;
      float v3 = acc[mi][ni][3] + bv;
      if (EPI == 1) {
        oF[(size_t)(mm + 0) * 1024 + nn] = v0;
        oF[(size_t)(mm + 1) * 1024 + nn] = v1;
        oF[(size_t)(mm + 2) * 1024 + nn] = v2;
        oF[(size_t)(mm + 3) * 1024 + nn] = v3;
      } else if (nn < 1024) {
        oQ[((size_t)hh * TSEQ + mm + 0) * 64 + dd] = f2bf(v0 * 0.125f);
        oQ[((size_t)hh * TSEQ + mm + 1) * 64 + dd] = f2bf(v1 * 0.125f);
        oQ[((size_t)hh * TSEQ + mm + 2) * 64 + dd] = f2bf(v2 * 0.125f);
        oQ[((size_t)hh * TSEQ + mm + 3) * 64 + dd] = f2bf(v3 * 0.125f);
      } else if (nn < 2048) {
        oK[((size_t)hh * TSEQ + mm + 0) * 64 + dd] = f2bf(v0);
        oK[((size_t)hh * TSEQ + mm + 1) * 64 + dd] = f2bf(v1);
        oK[((size_t)hh * TSEQ + mm + 2) * 64 + dd] = f2bf(v2);
        oK[((size_t)hh * TSEQ + mm + 3) * 64 + dd] = f2bf(v3);
      } else {
        unsigned lo = cvtpk(v0, v1), hi = cvtpk(v2, v3);
        unsigned long long pv = (unsigned long long)lo | ((unsigned long long)hi << 32);
        *(unsigned long long*)(oVT + ((size_t)hh * 64 + dd) * TSEQ + mm) = pv;
      }
    }
  }
}

// ---------------- sliding-window attention (LDS-staged, double-buffered) ----------------
// grid 1024 (XCD-swizzled -> 2 heads/XCD), 4 waves; wave w owns q rows qb*64+w*16..+15
// Per tile: 4 waves cooperatively stage K(8KB)+V(8KB) via global_load_lds (4 instrs/wave)
// into KV[buf], double-buffered with counted vmcnt(4) (loads for t+1 in flight over
// compute(t)). Source pre-swizzled (c ^ ((row&7)<<4)) + swizzled LDS reads (rule 21).
// S^T = mfma(K,Q); PV = mfma(V,P^T): softmax + rescale + 1/l all lane-local (q=lane&15).

__global__ __launch_bounds__(256)
void attn_swa(const unsigned short* __restrict__ Qa,
              const unsigned short* __restrict__ Ka,
              const unsigned short* __restrict__ Vt,
              unsigned short* __restrict__ Y) {
  __shared__ __align__(16) char KV[2][16384];   // [buf][ K 8KB | V 8KB ]
  __shared__ __align__(16) unsigned char Pl[4][2048];
  int flat = blockIdx.x;
  int swz = (flat & 7) * 128 + (flat >> 3);   // bijective; 2 heads/XCD
  int h = swz >> 6, qb = swz & 63;
  int w = threadIdx.x >> 6, lane = threadIdx.x & 63;
  int l15 = lane & 15, l4 = lane >> 4;
  int qrow0 = qb * 64 + w * 16;
  int q = qrow0 + l15;

  // Q fragments (pre-scaled by 1/8 in the QKV epilogue)
  const unsigned short* qp = Qa + ((size_t)h * TSEQ + q) * 64 + l4 * 8;
  short8 qf0 = *(const short8*)qp;
  short8 qf1 = *(const short8*)(qp + 32);

  const char* kgb = (const char*)(Ka + (size_t)h * TSEQ * 64);  // + (kbase+r)*128 bytes
  const char* vgb = (const char*)(Vt + (size_t)h * 64 * TSEQ);  // + d*8192 + kbase*2 + c

  // stage tile kt into buffer b: waves 0,1 -> K rows w*32..+31; waves 2,3 -> V d-rows
  auto stage = [&](int kt, int b) {
    int kbase = kt * 64;
    int sub = lane >> 3, slot = (lane & 7) * 16;
    if (w < 2) {
      int R0 = w * 32;
      const char* src = kgb + (size_t)kbase * 128;
#pragma unroll
      for (int j = 0; j < 4; j++) {
        int r = R0 + j * 8 + sub;
        g2lds16(src + r * 128 + (slot ^ ((r & 7) << 4)), &KV[b][R0 * 128 + j * 1024]);
      }
    } else {
      int D0 = (w - 2) * 32;
      const char* src = vgb + (size_t)kbase * 2;
#pragma unroll
      for (int j = 0; j < 4; j++) {
        int d = D0 + j * 8 + sub;
        g2lds16(src + (size_t)d * 8192 + (slot ^ ((d & 7) << 4)),
                &KV[b][8192 + D0 * 128 + j * 1024]);
      }
    }
  };

  float m = -1e30f, lsum = 0.f;
  f32x4 o[4];
#pragma unroll
  for (int ni = 0; ni < 4; ni++) o[ni] = (f32x4){0.f, 0.f, 0.f, 0.f};

  unsigned char* pw = Pl[w];
  int xw = (l15 & 7) << 4;  // row&7 == l15&7 for rows ni*16+l15

  // MODE: 0 = interior, 1 = window edge (q-key<256), 2 = causal diag (key<=q)
  auto compute = [&](int kt, int b, int MODE) {
    int kbase = kt * 64;
    const char* kb = KV[b];
    const char* vb = KV[b] + 8192;
    f32x4 s[4];
#pragma unroll
    for (int ni = 0; ni < 4; ni++) {
      int rb = (ni * 16 + l15) * 128;
      short8 k0 = *(const short8*)(kb + rb + ((l4 * 16) ^ xw));
      short8 k1 = *(const short8*)(kb + rb + ((64 + l4 * 16) ^ xw));
      f32x4 z = (f32x4){0.f, 0.f, 0.f, 0.f};
      z = mfma16(k0, qf0, z);
      s[ni] = mfma16(k1, qf1, z);
    }
    if (MODE != 0) {
#pragma unroll
      for (int ni = 0; ni < 4; ni++)
#pragma unroll
        for (int r = 0; r < 4; r++) {
          int key = kbase + ni * 16 + l4 * 4 + r;
          bool ok = (MODE == 2) ? (key <= q) : (q - key < WINDOW);
          s[ni][r] = ok ? s[ni][r] : -1e30f;
        }
    }
    float pm0 = fmaxf(fmaxf(s[0][0], s[0][1]), fmaxf(s[0][2], s[0][3]));
    float pm1 = fmaxf(fmaxf(s[1][0], s[1][1]), fmaxf(s[1][2], s[1][3]));
    float pm2 = fmaxf(fmaxf(s[2][0], s[2][1]), fmaxf(s[2][2], s[2][3]));
    float pm3 = fmaxf(fmaxf(s[3][0], s[3][1]), fmaxf(s[3][2], s[3][3]));
    float pm = fmaxf(fmaxf(pm0, pm1), fmaxf(pm2, pm3));
    pm = fmaxf(pm, __shfl_xor(pm, 16, 64));
    pm = fmaxf(pm, __shfl_xor(pm, 32, 64));
    float mn = fmaxf(m, pm);
    float alpha = __expf(m - mn);
    m = mn;
    float rs = 0.f;
#pragma unroll
    for (int ni = 0; ni < 4; ni++)
#pragma unroll
      for (int r = 0; r < 4; r++) {
        float p = __expf(s[ni][r] - mn);
        s[ni][r] = p;
        rs += p;
      }
    rs += __shfl_xor(rs, 16, 64);
    rs += __shfl_xor(rs, 32, 64);
    lsum = lsum * alpha + rs;
    // P -> per-wave LDS (cvt_pk packed, row-XOR swizzled both sides)
#pragma unroll
    for (int ni = 0; ni < 4; ni++) {
      unsigned lo = cvtpk(s[ni][0], s[ni][1]);
      unsigned hi = cvtpk(s[ni][2], s[ni][3]);
      unsigned long long pv = (unsigned long long)lo | ((unsigned long long)hi << 32);
      *(unsigned long long*)(pw + l15 * 128 + ((ni * 32 + l4 * 8) ^ xw)) = pv;
    }
    short8 pa0 = *(const short8*)(pw + l15 * 128 + ((l4 * 16) ^ xw));
    short8 pa1 = *(const short8*)(pw + l15 * 128 + ((64 + l4 * 16) ^ xw));
#pragma unroll
    for (int ni = 0; ni < 4; ni++)
#pragma unroll
      for (int r = 0; r < 4; r++) o[ni][r] *= alpha;
#pragma unroll
    for (int ni = 0; ni < 4; ni++) {
      int rb = (ni * 16 + l15) * 128;
      short8 v0 = *(const short8*)(vb + rb + ((l4 * 16) ^ xw));
      short8 v1 = *(const short8*)(vb + rb + ((64 + l4 * 16) ^ xw));
      o[ni] = mfma16(v0, pa0, o[ni]);
      o[ni] = mfma16(v1, pa1, o[ni]);
    }
  };

  int kt0 = qb >= 4 ? qb - 4 : 0;
  int NT = qb - kt0 + 1;
  stage(kt0, 0);
  for (int t = 0; t < NT; t++) {
    int kt = kt0 + t;
    if (t + 1 < NT) {
      stage(kt + 1, (t + 1) & 1);
      asm volatile("s_waitcnt vmcnt(4)" ::: "memory");  // stage(t) done; stage(t+1) in flight
    } else {
      asm volatile("s_waitcnt vmcnt(0)" ::: "memory");
    }
    __builtin_amdgcn_s_barrier();
    __builtin_amdgcn_sched_barrier(0);
    int MODE = (t == NT - 1) ? 2 : ((qb >= 4 && t == 0) ? 1 : 0);
    compute(kt, t & 1, MODE);
    __builtin_amdgcn_sched_barrier(0);
    __builtin_amdgcn_s_barrier();   // all waves done reading buf before it's restaged
  }

  float inv = 1.f / lsum;
#pragma unroll
  for (int ni = 0; ni < 4; ni++) {
    unsigned lo = cvtpk(o[ni][0] * inv, o[ni][1] * inv);
    unsigned hi = cvtpk(o[ni][2] * inv, o[ni][3] * inv);
    unsigned long long yv = (unsigned long long)lo | ((unsigned long long)hi << 32);
    *(unsigned long long*)(Y + (size_t)q * DMODEL + h * 64 + ni * 16 + l4 * 4) = yv;
  }
}

// ---------------- launch ----------------

extern "C" void kernel_launch(void* const* d_in, const int* in_sizes, int n_in,
                              void* d_out, int out_size, void* d_ws, size_t ws_size,
                              hipStream_t stream) {
  const float* x = (const float*)d_in[0];
  const float* Wqkv = (const float*)d_in[1];
  const float* bqkv = (const float*)d_in[2];
  const float* Wproj = (const float*)d_in[3];
  const float* bproj = (const float*)d_in[4];
  float* out = (float*)d_out;

  unsigned short* ws = (unsigned short*)d_ws;
  unsigned short* xb = ws;                                        // [4096][1024]
  unsigned short* wqkvT = xb + (size_t)TSEQ * DMODEL;             // [3072][1024]
  unsigned short* wprojT = wqkvT + (size_t)N3 * DMODEL;           // [1024][1024]
  unsigned short* qarr = wprojT + (size_t)DMODEL * DMODEL;        // [16][4096][64] (pre-scaled 1/8)
  unsigned short* karr = qarr + (size_t)NHEADS * TSEQ * HDIM;     // [16][4096][64]
  unsigned short* vtarr = karr + (size_t)NHEADS * TSEQ * HDIM;    // [16][64][4096]
  unsigned short* yarr = vtarr + (size_t)NHEADS * TSEQ * HDIM;    // [4096][1024]

  cvt_f32_bf16_v4<<<(TSEQ * DMODEL) / 1024, 256, 0, stream>>>(x, xb);
  transpose_cvt2<<<dim3(128, 32), dim3(32, 8), 0, stream>>>(Wqkv, Wproj, wqkvT, wprojT);
  gemm_bf16_128<0><<<dim3(TSEQ / 128, N3 / 128), 256, 0, stream>>>(xb, wqkvT, bqkv, qarr, karr, vtarr, nullptr);
  attn_swa<<<1024, 256, 0, stream>>>(qarr, karr, vtarr, yarr);
  gemm_bf16_128<1><<<dim3(TSEQ / 128, DMODEL / 128), 256, 0, stream>>>(yarr, wprojT, bproj, nullptr, nullptr, nullptr, out);
}

// Round 5
// 85.550 us; speedup vs baseline: 1.6496x; 1.1287x over previous
//
#include <hip/hip_runtime.h>
#include <stdint.h>

#define TSEQ 4096
#define DMODEL 1024
#define N3 3072
#define NHEADS 16
#define HDIM 64
#define WINDOW 256

typedef __attribute__((ext_vector_type(8))) short short8;
typedef __attribute__((ext_vector_type(4))) float f32x4;

__device__ __forceinline__ unsigned short f2bf(float f) {
  unsigned u = __builtin_bit_cast(unsigned, f);
  return (unsigned short)((u + 0x7fffu + ((u >> 16) & 1u)) >> 16);
}

__device__ __forceinline__ unsigned cvtpk(float lo, float hi) {
  unsigned r;
  asm("v_cvt_pk_bf16_f32 %0, %1, %2" : "=v"(r) : "v"(lo), "v"(hi));
  return r;
}

__device__ __forceinline__ f32x4 mfma16(short8 a, short8 b, f32x4 c) {
  return __builtin_amdgcn_mfma_f32_16x16x32_bf16(a, b, c, 0, 0, 0);
}

// async global->LDS, 16B per lane; lds dest must be wave-uniform base (HW adds lane*16)
__device__ __forceinline__ void g2lds16(const void* g, void* l) {
  __builtin_amdgcn_global_load_lds(
      (const __attribute__((address_space(1))) void*)(uintptr_t)g,
      (__attribute__((address_space(3))) void*)(uintptr_t)l,
      16, 0, 0);
}

// ---------------- convert / transpose ----------------

__global__ __launch_bounds__(256) void cvt_f32_bf16_v4(const float* __restrict__ in,
                                                       unsigned short* __restrict__ out) {
  int i = (blockIdx.x * 256 + threadIdx.x) * 4;
  float4 v = *(const float4*)(in + i);
  unsigned lo = cvtpk(v.x, v.y), hi = cvtpk(v.z, v.w);
  unsigned long long packed = (unsigned long long)lo | ((unsigned long long)hi << 32);
  *(unsigned long long*)(out + i) = packed;
}

// fused: Wqkv [1024][3072] -> [3072][1024] bf16, Wproj [1024][1024] -> [1024][1024] bf16
__global__ __launch_bounds__(256) void transpose_cvt2(const float* __restrict__ Wqkv,
                                                      const float* __restrict__ Wproj,
                                                      unsigned short* __restrict__ oQkvT,
                                                      unsigned short* __restrict__ oProjT) {
  __shared__ float tile[32][33];
  int bx = blockIdx.x;
  const float* in;
  unsigned short* out;
  int C;
  if (bx < 96) {
    in = Wqkv; out = oQkvT; C = N3;
  } else {
    bx -= 96; in = Wproj; out = oProjT; C = DMODEL;
  }
  const int R = DMODEL;
  int c0 = bx * 32;
  int r0 = blockIdx.y * 32;
  int tx = threadIdx.x, ty = threadIdx.y;
#pragma unroll
  for (int i = 0; i < 32; i += 8)
    tile[ty + i][tx] = in[(size_t)(r0 + ty + i) * C + c0 + tx];
  __syncthreads();
#pragma unroll
  for (int i = 0; i < 32; i += 8)
    out[(size_t)(c0 + ty + i) * R + r0 + tx] = f2bf(tile[tx][ty + i]);
}

// ---------------- GEMM: C[M][N] = A[M][K=1024] * BT[N][K]^T + bias ----------------
// EPI=0: scatter to Q[h][t][d] (pre-scaled by 1/8), K[h][t][d], VT[h][d][t] (bf16)
// EPI=1: f32 out [M][1024]
// K-loop: 32 half-steps of BK=32, ping-pong LDS (32KB total -> 3 blocks/CU kept),
// counted vmcnt(4): stage(s+1) stays in flight across compute(s) (round-3 attn pattern).
// Staging source pre-swizzled by ((row>>1)&3)<<4, same XOR on LDS read (rule 21):
// bank group becomes (r&1)*4 + (l4 ^ ((r>>1)&3)) -> 2-way only (free, m136).

template <int EPI>
__global__ __launch_bounds__(256)
void gemm_bf16_128(const unsigned short* __restrict__ A,
                   const unsigned short* __restrict__ BT,
                   const float* __restrict__ bias,
                   unsigned short* __restrict__ oQ,
                   unsigned short* __restrict__ oK,
                   unsigned short* __restrict__ oVT,
                   float* __restrict__ oF) {
  __shared__ unsigned short Asm[2][128 * 32];
  __shared__ unsigned short Bsm[2][128 * 32];
  const int K = 1024;
  int m0 = blockIdx.x * 128;   // no XCD swizzle: default bx%8 partitioning already
  int n0 = blockIdx.y * 128;   // splits A-panels across XCDs (round-2 post-mortem)
  int tid = threadIdx.x;
  int w = tid >> 6, lane = tid & 63;
  int l15 = lane & 15, l4 = lane >> 4;
  int wm = (w >> 1) * 64, wn = (w & 1) * 64;

  f32x4 acc[4][4];
#pragma unroll
  for (int i = 0; i < 4; i++)
#pragma unroll
    for (int j = 0; j < 4; j++) acc[i][j] = (f32x4){0.f, 0.f, 0.f, 0.f};

  // staging: wave w covers A rows w*32..+31 and B rows w*32..+31 (two 16-row chunks).
  // lane -> local row lr = lane>>2, slot byte (lane&3)*16 XOR ((lr>>1)&3)<<4 (pre-swizzle)
  int lr = lane >> 2;
  int slot = ((lane & 3) * 16) ^ (((lr >> 1) & 3) << 4);
  const char* aG = (const char*)(A + (size_t)(m0 + w * 32 + lr) * K) + slot;
  const char* bG = (const char*)(BT + (size_t)(n0 + w * 32 + lr) * K) + slot;
  const size_t rowSkip = (size_t)16 * K * 2;  // +16 rows, bytes

  auto stage = [&](int s, int b) {   // half-step s covers k = s*32..s*32+31
    int koff = s * 64;               // bytes within row
    g2lds16(aG + koff, &Asm[b][w * 1024]);
    g2lds16(aG + rowSkip + koff, &Asm[b][w * 1024 + 512]);
    g2lds16(bG + koff, &Bsm[b][w * 1024]);
    g2lds16(bG + rowSkip + koff, &Bsm[b][w * 1024 + 512]);
  };

  int sX = ((l15 >> 1) & 3) << 4;    // read-side swizzle (row bits 1-2 == l15 bits 1-2)

  auto compute = [&](int b) {
    short8 af[4], bfr[4];
#pragma unroll
    for (int mi = 0; mi < 4; mi++) {
      int rA = wm + mi * 16 + l15;
      af[mi] = *(const short8*)((const char*)Asm[b] + rA * 64 + ((l4 * 16) ^ sX));
    }
#pragma unroll
    for (int ni = 0; ni < 4; ni++) {
      int rB = wn + ni * 16 + l15;
      bfr[ni] = *(const short8*)((const char*)Bsm[b] + rB * 64 + ((l4 * 16) ^ sX));
    }
#pragma unroll
    for (int mi = 0; mi < 4; mi++)
#pragma unroll
      for (int ni = 0; ni < 4; ni++)
        acc[mi][ni] = mfma16(af[mi], bfr[ni], acc[mi][ni]);
  };

  const int NS = K / 32;  // 32 half-steps
  stage(0, 0);
  for (int s = 0; s < NS; s++) {
    if (s + 1 < NS) {
      stage(s + 1, (s + 1) & 1);
      asm volatile("s_waitcnt vmcnt(4)" ::: "memory");  // stage(s) done; stage(s+1) in flight
    } else {
      asm volatile("s_waitcnt vmcnt(0)" ::: "memory");
    }
    __builtin_amdgcn_s_barrier();
    __builtin_amdgcn_sched_barrier(0);
    compute(s & 1);
    __builtin_amdgcn_sched_barrier(0);
    __builtin_amdgcn_s_barrier();   // all waves done reading buf before it's restaged
  }

#pragma unroll
  for (int ni = 0; ni < 4; ni++) {
    int nn = n0 + wn + ni * 16 + l15;
    float bv = bias[nn];
    int c = nn & 1023;
    int hh = c >> 6, dd = c & 63;
#pragma unroll
    for (int mi = 0; mi < 4; mi++) {
      int mm = m0 + wm + mi * 16 + l4 * 4;
      float v0 = acc[mi][ni][0] + bv;
      float v1 = acc[mi][ni][1] + bv;
      float v2 = acc[mi][ni][2] + bv;
      float v3 = acc[mi][ni][3] + bv;
      if (EPI == 1) {
        oF[(size_t)(mm + 0) * 1024 + nn] = v0;
        oF[(size_t)(mm + 1) * 1024 + nn] = v1;
        oF[(size_t)(mm + 2) * 1024 + nn] = v2;
        oF[(size_t)(mm + 3) * 1024 + nn] = v3;
      } else if (nn < 1024) {
        oQ[((size_t)hh * TSEQ + mm + 0) * 64 + dd] = f2bf(v0 * 0.125f);
        oQ[((size_t)hh * TSEQ + mm + 1) * 64 + dd] = f2bf(v1 * 0.125f);
        oQ[((size_t)hh * TSEQ + mm + 2) * 64 + dd] = f2bf(v2 * 0.125f);
        oQ[((size_t)hh * TSEQ + mm + 3) * 64 + dd] = f2bf(v3 * 0.125f);
      } else if (nn < 2048) {
        oK[((size_t)hh * TSEQ + mm + 0) * 64 + dd] = f2bf(v0);
        oK[((size_t)hh * TSEQ + mm + 1) * 64 + dd] = f2bf(v1);
        oK[((size_t)hh * TSEQ + mm + 2) * 64 + dd] = f2bf(v2);
        oK[((size_t)hh * TSEQ + mm + 3) * 64 + dd] = f2bf(v3);
      } else {
        unsigned lo = cvtpk(v0, v1), hi = cvtpk(v2, v3);
        unsigned long long pv = (unsigned long long)lo | ((unsigned long long)hi << 32);
        *(unsigned long long*)(oVT + ((size_t)hh * 64 + dd) * TSEQ + mm) = pv;
      }
    }
  }
}

// ---------------- sliding-window attention (LDS-staged, double-buffered) ----------------
// grid 1024 (XCD-swizzled -> 2 heads/XCD), 4 waves; wave w owns q rows qb*64+w*16..+15
// Per tile: 4 waves cooperatively stage K(8KB)+V(8KB) via global_load_lds, double-buffered
// with counted vmcnt(4). Source pre-swizzled + swizzled LDS reads (rule 21).
// S^T = mfma(K,Q); PV = mfma(V,P^T): softmax + rescale + 1/l all lane-local (q=lane&15).

__global__ __launch_bounds__(256)
void attn_swa(const unsigned short* __restrict__ Qa,
              const unsigned short* __restrict__ Ka,
              const unsigned short* __restrict__ Vt,
              unsigned short* __restrict__ Y) {
  __shared__ __align__(16) char KV[2][16384];   // [buf][ K 8KB | V 8KB ]
  __shared__ __align__(16) unsigned char Pl[4][2048];
  int flat = blockIdx.x;
  int swz = (flat & 7) * 128 + (flat >> 3);   // bijective; 2 heads/XCD
  int h = swz >> 6, qb = swz & 63;
  int w = threadIdx.x >> 6, lane = threadIdx.x & 63;
  int l15 = lane & 15, l4 = lane >> 4;
  int qrow0 = qb * 64 + w * 16;
  int q = qrow0 + l15;

  // Q fragments (pre-scaled by 1/8 in the QKV epilogue)
  const unsigned short* qp = Qa + ((size_t)h * TSEQ + q) * 64 + l4 * 8;
  short8 qf0 = *(const short8*)qp;
  short8 qf1 = *(const short8*)(qp + 32);

  const char* kgb = (const char*)(Ka + (size_t)h * TSEQ * 64);
  const char* vgb = (const char*)(Vt + (size_t)h * 64 * TSEQ);

  // stage tile kt into buffer b: waves 0,1 -> K rows w*32..+31; waves 2,3 -> V d-rows
  auto stage = [&](int kt, int b) {
    int kbase = kt * 64;
    int sub = lane >> 3, slot = (lane & 7) * 16;
    if (w < 2) {
      int R0 = w * 32;
      const char* src = kgb + (size_t)kbase * 128;
#pragma unroll
      for (int j = 0; j < 4; j++) {
        int r = R0 + j * 8 + sub;
        g2lds16(src + r * 128 + (slot ^ ((r & 7) << 4)), &KV[b][R0 * 128 + j * 1024]);
      }
    } else {
      int D0 = (w - 2) * 32;
      const char* src = vgb + (size_t)kbase * 2;
#pragma unroll
      for (int j = 0; j < 4; j++) {
        int d = D0 + j * 8 + sub;
        g2lds16(src + (size_t)d * 8192 + (slot ^ ((d & 7) << 4)),
                &KV[b][8192 + D0 * 128 + j * 1024]);
      }
    }
  };

  float m = -1e30f, lsum = 0.f;
  f32x4 o[4];
#pragma unroll
  for (int ni = 0; ni < 4; ni++) o[ni] = (f32x4){0.f, 0.f, 0.f, 0.f};

  unsigned char* pw = Pl[w];
  int xw = (l15 & 7) << 4;  // row&7 == l15&7 for rows ni*16+l15

  // MODE: 0 = interior, 1 = window edge (q-key<256), 2 = causal diag (key<=q)
  auto compute = [&](int kt, int b, int MODE) {
    int kbase = kt * 64;
    const char* kb = KV[b];
    const char* vb = KV[b] + 8192;
    f32x4 s[4];
#pragma unroll
    for (int ni = 0; ni < 4; ni++) {
      int rb = (ni * 16 + l15) * 128;
      short8 k0 = *(const short8*)(kb + rb + ((l4 * 16) ^ xw));
      short8 k1 = *(const short8*)(kb + rb + ((64 + l4 * 16) ^ xw));
      f32x4 z = (f32x4){0.f, 0.f, 0.f, 0.f};
      z = mfma16(k0, qf0, z);
      s[ni] = mfma16(k1, qf1, z);
    }
    if (MODE != 0) {
#pragma unroll
      for (int ni = 0; ni < 4; ni++)
#pragma unroll
        for (int r = 0; r < 4; r++) {
          int key = kbase + ni * 16 + l4 * 4 + r;
          bool ok = (MODE == 2) ? (key <= q) : (q - key < WINDOW);
          s[ni][r] = ok ? s[ni][r] : -1e30f;
        }
    }
    float pm0 = fmaxf(fmaxf(s[0][0], s[0][1]), fmaxf(s[0][2], s[0][3]));
    float pm1 = fmaxf(fmaxf(s[1][0], s[1][1]), fmaxf(s[1][2], s[1][3]));
    float pm2 = fmaxf(fmaxf(s[2][0], s[2][1]), fmaxf(s[2][2], s[2][3]));
    float pm3 = fmaxf(fmaxf(s[3][0], s[3][1]), fmaxf(s[3][2], s[3][3]));
    float pm = fmaxf(fmaxf(pm0, pm1), fmaxf(pm2, pm3));
    pm = fmaxf(pm, __shfl_xor(pm, 16, 64));
    pm = fmaxf(pm, __shfl_xor(pm, 32, 64));
    float mn = fmaxf(m, pm);
    float alpha = __expf(m - mn);
    m = mn;
    float rs = 0.f;
#pragma unroll
    for (int ni = 0; ni < 4; ni++)
#pragma unroll
      for (int r = 0; r < 4; r++) {
        float p = __expf(s[ni][r] - mn);
        s[ni][r] = p;
        rs += p;
      }
    rs += __shfl_xor(rs, 16, 64);
    rs += __shfl_xor(rs, 32, 64);
    lsum = lsum * alpha + rs;
    // P -> per-wave LDS (cvt_pk packed, row-XOR swizzled both sides)
#pragma unroll
    for (int ni = 0; ni < 4; ni++) {
      unsigned lo = cvtpk(s[ni][0], s[ni][1]);
      unsigned hi = cvtpk(s[ni][2], s[ni][3]);
      unsigned long long pv = (unsigned long long)lo | ((unsigned long long)hi << 32);
      *(unsigned long long*)(pw + l15 * 128 + ((ni * 32 + l4 * 8) ^ xw)) = pv;
    }
    short8 pa0 = *(const short8*)(pw + l15 * 128 + ((l4 * 16) ^ xw));
    short8 pa1 = *(const short8*)(pw + l15 * 128 + ((64 + l4 * 16) ^ xw));
#pragma unroll
    for (int ni = 0; ni < 4; ni++)
#pragma unroll
      for (int r = 0; r < 4; r++) o[ni][r] *= alpha;
#pragma unroll
    for (int ni = 0; ni < 4; ni++) {
      int rb = (ni * 16 + l15) * 128;
      short8 v0 = *(const short8*)(vb + rb + ((l4 * 16) ^ xw));
      short8 v1 = *(const short8*)(vb + rb + ((64 + l4 * 16) ^ xw));
      o[ni] = mfma16(v0, pa0, o[ni]);
      o[ni] = mfma16(v1, pa1, o[ni]);
    }
  };

  int kt0 = qb >= 4 ? qb - 4 : 0;
  int NT = qb - kt0 + 1;
  stage(kt0, 0);
  for (int t = 0; t < NT; t++) {
    int kt = kt0 + t;
    if (t + 1 < NT) {
      stage(kt + 1, (t + 1) & 1);
      asm volatile("s_waitcnt vmcnt(4)" ::: "memory");
    } else {
      asm volatile("s_waitcnt vmcnt(0)" ::: "memory");
    }
    __builtin_amdgcn_s_barrier();
    __builtin_amdgcn_sched_barrier(0);
    int MODE = (t == NT - 1) ? 2 : ((qb >= 4 && t == 0) ? 1 : 0);
    compute(kt, t & 1, MODE);
    __builtin_amdgcn_sched_barrier(0);
    __builtin_amdgcn_s_barrier();
  }

  float inv = 1.f / lsum;
#pragma unroll
  for (int ni = 0; ni < 4; ni++) {
    unsigned lo = cvtpk(o[ni][0] * inv, o[ni][1] * inv);
    unsigned hi = cvtpk(o[ni][2] * inv, o[ni][3] * inv);
    unsigned long long yv = (unsigned long long)lo | ((unsigned long long)hi << 32);
    *(unsigned long long*)(Y + (size_t)q * DMODEL + h * 64 + ni * 16 + l4 * 4) = yv;
  }
}

// ---------------- launch ----------------

extern "C" void kernel_launch(void* const* d_in, const int* in_sizes, int n_in,
                              void* d_out, int out_size, void* d_ws, size_t ws_size,
                              hipStream_t stream) {
  const float* x = (const float*)d_in[0];
  const float* Wqkv = (const float*)d_in[1];
  const float* bqkv = (const float*)d_in[2];
  const float* Wproj = (const float*)d_in[3];
  const float* bproj = (const float*)d_in[4];
  float* out = (float*)d_out;

  unsigned short* ws = (unsigned short*)d_ws;
  unsigned short* xb = ws;                                        // [4096][1024]
  unsigned short* wqkvT = xb + (size_t)TSEQ * DMODEL;             // [3072][1024]
  unsigned short* wprojT = wqkvT + (size_t)N3 * DMODEL;           // [1024][1024]
  unsigned short* qarr = wprojT + (size_t)DMODEL * DMODEL;        // [16][4096][64] (pre-scaled 1/8)
  unsigned short* karr = qarr + (size_t)NHEADS * TSEQ * HDIM;     // [16][4096][64]
  unsigned short* vtarr = karr + (size_t)NHEADS * TSEQ * HDIM;    // [16][64][4096]
  unsigned short* yarr = vtarr + (size_t)NHEADS * TSEQ * HDIM;    // [4096][1024]

  cvt_f32_bf16_v4<<<(TSEQ * DMODEL) / 1024, 256, 0, stream>>>(x, xb);
  transpose_cvt2<<<dim3(128, 32), dim3(32, 8), 0, stream>>>(Wqkv, Wproj, wqkvT, wprojT);
  gemm_bf16_128<0><<<dim3(TSEQ / 128, N3 / 128), 256, 0, stream>>>(xb, wqkvT, bqkv, qarr, karr, vtarr, nullptr);
  attn_swa<<<1024, 256, 0, stream>>>(qarr, karr, vtarr, yarr);
  gemm_bf16_128<1><<<dim3(TSEQ / 128, DMODEL / 128), 256, 0, stream>>>(yarr, wprojT, bproj, nullptr, nullptr, nullptr, out);
}